// Round 6
// baseline (316.632 us; speedup 1.0000x reference)
//
#include <hip/hip_runtime.h>
#include <math.h>

#define B_ 16
#define C_ 384
#define N_ 1024
#define K_ 9

typedef _Float16 f16x8 __attribute__((ext_vector_type(8)));
typedef _Float16 f16x4 __attribute__((ext_vector_type(4)));
typedef float f32x4 __attribute__((ext_vector_type(4)));
typedef unsigned long long u64;

__device__ __forceinline__ void gld_lds16(const void* g, void* l) {
  __builtin_amdgcn_global_load_lds((const __attribute__((address_space(1))) void*)g,
                                   (__attribute__((address_space(3))) void*)l, 16, 0, 0);
}

__device__ __forceinline__ void ce9(u64& a, u64& b) {
  u64 lo = a < b ? a : b;
  u64 hi = a < b ? b : a;
  a = lo;
  b = hi;
}

// ---------------- transpose + fp16 split: x[b][c][n] -> xhT/xlT [b][n][c] ----------------
__global__ void k_cvt(const float* __restrict__ x, ushort* __restrict__ xhT,
                      ushort* __restrict__ xlT) {
  const int bid = blockIdx.x;  // ((b*16 + nt)*12 + ct)
  const int ct = bid % 12;
  const int nt = (bid / 12) & 15;
  const int b = bid / 192;
  const int c0 = ct * 32, n0 = nt * 64;
  __shared__ float ld[32 * 65];
  const int t = threadIdx.x;
  {
    const int c = t >> 3, n8 = (t & 7) * 8;
    const float* src = x + ((size_t)(b * C_ + c0 + c) * N_ + n0 + n8);
    float4 v0 = *(const float4*)src;
    float4 v1 = *(const float4*)(src + 4);
    float vv[8] = {v0.x, v0.y, v0.z, v0.w, v1.x, v1.y, v1.z, v1.w};
#pragma unroll
    for (int j = 0; j < 8; ++j) ld[c * 65 + n8 + j] = vv[j];
  }
  __syncthreads();
  {
    const int n = t >> 2, c8 = (t & 3) * 8;
    f16x8 hv, lv;
#pragma unroll
    for (int j = 0; j < 8; ++j) {
      float v = ld[(c8 + j) * 65 + n];
      _Float16 h = (_Float16)v;
      _Float16 l = (_Float16)(v - (float)h);
      hv[j] = h;
      lv[j] = l;
    }
    const size_t off = (size_t)(b * N_ + n0 + n) * C_ + c0 + c8;
    *(f16x8*)(xhT + off) = hv;
    *(f16x8*)(xlT + off) = lv;
  }
}

// ---------------- Wg -> WgH/WgL ----------------
__global__ void k_cvtw(const float* __restrict__ Wg, ushort* __restrict__ WgH,
                       ushort* __restrict__ WgL) {
  const int i = (blockIdx.x * 256 + threadIdx.x) * 4;  // 144 blocks
  float4 v = *(const float4*)(Wg + i);
  float vv[4] = {v.x, v.y, v.z, v.w};
  f16x4 hv, lv;
#pragma unroll
  for (int j = 0; j < 4; ++j) {
    _Float16 h = (_Float16)vv[j];
    hv[j] = h;
    lv[j] = (_Float16)(vv[j] - (float)h);
  }
  *(f16x4*)(WgH + i) = hv;
  *(f16x4*)(WgL + i) = lv;
}

// ---------------- sq[b][n] = sum_c x[b][c][n]^2 (fp64 accum) ----------------
__global__ void k_sq(const float* __restrict__ x, float* __restrict__ sq) {
  const int idx = blockIdx.x * blockDim.x + threadIdx.x;
  const int b = idx >> 10, n = idx & 1023;
  const float* xb = x + (size_t)b * C_ * N_ + n;
  double s = 0.0;
#pragma unroll 4
  for (int c = 0; c < C_; ++c) {
    float v = xb[(size_t)c * N_];
    s = fma((double)v, (double)v, s);
  }
  sq[idx] = (float)s;
}

// ---------------- MFMA Gram 128x128 + fused per-(node,tile) top-9 ----------------
// grid 1024, single dispatch. XCD swizzle: x=bid&7 -> batches {2x,2x+1} (L2-resident
// panels). Main loop identical to R5 (dbuf global_load_lds staging, prefetch dist 1).
// Epilogue: distances to LDS overlay D_l[64][132] (both staging bufs dead, 65KB);
// 4 threads/row build sorted-9 u64 (mono(d)<<32|idx) over 32-col chunks, combined by
// 2 shfl_xor levels of the R5-verified capped bitonic merge. ck[mt][node] = 9.4MB
// total -- replaces the 67MB D round-trip that made k_scan memory-bound.
__global__ __launch_bounds__(256, 2) void k_gram(const ushort* __restrict__ xhT,
                                                 const ushort* __restrict__ xlT,
                                                 const float* __restrict__ sq,
                                                 u64* __restrict__ ck) {
  const int bid = blockIdx.x;
  const int xg = bid & 7, j = bid >> 3;
  const int b = xg * 2 + (j >> 6);
  const int pid = j & 63;
  const int rt = pid >> 3, mt = pid & 7;
  const int n0 = rt * 128, m0 = mt * 128;

  __shared__ alignas(16) char sm[2][32768];
  const int t = threadIdx.x;
  const int lane = t & 63, wid = t >> 6, quad = lane >> 4, lrow = lane & 15;
  const int wr = wid >> 1, wc = wid & 1;
  const int lrow4 = lane >> 2, lpos = lane & 3;

  // wave -> array it stages: 0:Ah(n0,h) 1:Al(n0,l) 2:Bh(m0,h) 3:Bl(m0,l)
  const char* src = (const char*)((wid & 1) ? xlT : xhT) +
                    (size_t)(b * N_ + ((wid >> 1) ? m0 : n0)) * C_ * 2;

  f32x4 acc[4][4];
#pragma unroll
  for (int mi = 0; mi < 4; ++mi)
#pragma unroll
    for (int ni = 0; ni < 4; ++ni) acc[mi][ni] = (f32x4){0.f, 0.f, 0.f, 0.f};

  auto stage = [&](int it) {
    char* dst = sm[it & 1] + wid * 8192;
    const int ktB = it * 64;
#pragma unroll
    for (int i = 0; i < 8; ++i) {
      const int row = i * 16 + lrow4;
      const int swz = lpos ^ ((row >> 1) & 3);
      gld_lds16(src + (size_t)row * 768 + ktB + swz * 16, dst + i * 1024 + lane * 16);
    }
  };

  stage(0);
  for (int it = 0; it < 12; ++it) {
    __syncthreads();
    if (it < 11) stage(it + 1);
    const char* smb = sm[it & 1];
    f16x8 ah[4], al[4];
#pragma unroll
    for (int mi = 0; mi < 4; ++mi) {
      const int row = wr * 64 + mi * 16 + lrow;
      const int off = row * 64 + (quad ^ ((row >> 1) & 3)) * 16;
      ah[mi] = *(const f16x8*)(smb + off);
      al[mi] = *(const f16x8*)(smb + 8192 + off);
    }
#pragma unroll
    for (int ni = 0; ni < 4; ++ni) {
      const int row = wc * 64 + ni * 16 + lrow;
      const int off = row * 64 + (quad ^ ((row >> 1) & 3)) * 16;
      f16x8 bh = *(const f16x8*)(smb + 16384 + off);
      f16x8 bl = *(const f16x8*)(smb + 24576 + off);
#pragma unroll
      for (int mi = 0; mi < 4; ++mi) {
        acc[mi][ni] = __builtin_amdgcn_mfma_f32_16x16x32_f16(ah[mi], bh, acc[mi][ni], 0, 0, 0);
        acc[mi][ni] = __builtin_amdgcn_mfma_f32_16x16x32_f16(al[mi], bh, acc[mi][ni], 0, 0, 0);
        acc[mi][ni] = __builtin_amdgcn_mfma_f32_16x16x32_f16(ah[mi], bl, acc[mi][ni], 0, 0, 0);
      }
    }
  }

  // ---- fused epilogue: d -> D_l -> per-row top-9 ----
  const float* sqb = sq + b * N_;
  float sqm[4];
#pragma unroll
  for (int ni = 0; ni < 4; ++ni) sqm[ni] = sqb[m0 + wc * 64 + ni * 16 + lrow];
  float sqn_[4][4];
#pragma unroll
  for (int mi = 0; mi < 4; ++mi)
#pragma unroll
    for (int r = 0; r < 4; ++r) sqn_[mi][r] = sqb[n0 + wr * 64 + mi * 16 + quad * 4 + r];

  float* D = (float*)sm;  // 64 rows x stride 132 = 33792 B (staging dead)
  const int srow = t >> 2, p = t & 3;

  for (int ph = 0; ph < 2; ++ph) {
    __syncthreads();
    if (wr == ph) {
#pragma unroll
      for (int mi = 0; mi < 4; ++mi)
#pragma unroll
        for (int ni = 0; ni < 4; ++ni)
#pragma unroll
          for (int r = 0; r < 4; ++r) {
            const int rl = mi * 16 + quad * 4 + r;    // 0..63
            const int cl = wc * 64 + ni * 16 + lrow;  // 0..127
            const int ng = n0 + ph * 64 + rl, mg = m0 + cl;
            float d = fmaf(-2.f, acc[mi][ni][r], sqn_[mi][r] + sqm[ni]);
            if (ng == mg) d = 3.402823466e38f;
            D[rl * 132 + cl] = d;
          }
    }
    __syncthreads();
    // 4 threads per row, 32 contiguous cols each; ascending idx => stable ties
    u64 key[9];
#pragma unroll
    for (int k = 0; k < 9; ++k) key[k] = ~0ULL;
    const float* Drow = D + srow * 132 + p * 32;
#pragma unroll
    for (int i = 0; i < 8; ++i) {
      float4 v = *(const float4*)(Drow + i * 4);
      float vv[4] = {v.x, v.y, v.z, v.w};
#pragma unroll
      for (int jj = 0; jj < 4; ++jj) {
        unsigned fb = __float_as_uint(vv[jj]);
        unsigned mono = (fb >> 31) ? ~fb : (fb | 0x80000000u);
        u64 kk = ((u64)mono << 32) | (unsigned)(m0 + p * 32 + i * 4 + jj);
        if (kk < key[8]) {
          key[8] = kk;
#pragma unroll
          for (int s = 8; s >= 1; --s) ce9(key[s - 1], key[s]);
        }
      }
    }
    // combine the 4 chunk-partials (lanes t^1, t^2 hold same row)
#pragma unroll
    for (int lvl = 1; lvl <= 2; lvl <<= 1) {
      u64 pk[9];
#pragma unroll
      for (int k = 0; k < 9; ++k) pk[k] = __shfl_xor(key[k], lvl, 64);
      u64 m[9];
#pragma unroll
      for (int k = 0; k < 9; ++k) m[k] = key[k] < pk[8 - k] ? key[k] : pk[8 - k];
      ce9(m[0], m[8]);
      ce9(m[1], m[5]); ce9(m[2], m[6]); ce9(m[3], m[7]); ce9(m[4], m[8]);
      ce9(m[1], m[3]); ce9(m[2], m[4]); ce9(m[5], m[7]); ce9(m[6], m[8]);
      ce9(m[1], m[2]); ce9(m[3], m[4]); ce9(m[5], m[6]); ce9(m[7], m[8]);
#pragma unroll
      for (int k = 0; k < 9; ++k) key[k] = m[k];
    }
    if (p == 0) {
      const int node = b * N_ + n0 + ph * 64 + srow;
#pragma unroll
      for (int k = 0; k < 9; ++k) ck[(size_t)(mt * 9 + k) * (B_ * N_) + node] = key[k];
    }
  }
}

// ---------------- stable 8-way merge of sorted u64 9-lists ----------------
__global__ void k_merge(const u64* __restrict__ ck, int* __restrict__ nbr) {
  const int node = blockIdx.x * blockDim.x + threadIdx.x;
  u64 rd[9];
#pragma unroll
  for (int k = 0; k < 9; ++k) rd[k] = ck[(size_t)k * (B_ * N_) + node];
#pragma unroll
  for (int l = 1; l < 8; ++l) {
#pragma unroll
    for (int e = 0; e < 9; ++e) {
      u64 kk = ck[(size_t)(l * 9 + e) * (B_ * N_) + node];
      if (kk < rd[8]) {
        rd[8] = kk;
#pragma unroll
        for (int s = 8; s >= 1; --s) ce9(rd[s - 1], rd[s]);
      }
    }
  }
#pragma unroll
  for (int k = 0; k < 9; ++k) nbr[(size_t)node * K_ + k] = (int)(unsigned)(rd[k] & 0xFFFFFFFFu);
}

// ---------------- MFMA xw[b][co][n]: A=Wg(h/l), B=xT(h/l), dbuf staging ----------------
__global__ __launch_bounds__(256, 3) void k_xw(const ushort* __restrict__ xhT,
                                               const ushort* __restrict__ xlT,
                                               const ushort* __restrict__ WgH,
                                               const ushort* __restrict__ WgL,
                                               float* __restrict__ xw) {
  const int bid = blockIdx.x;  // ((b*8 + nt)*6 + ct)
  const int ct = bid % 6;
  const int nt = (bid / 6) & 7;
  const int b = bid / 48;
  const int co0 = ct * 64, n0 = nt * 128;
  __shared__ alignas(16) char sm[2][24576];  // per buf: Ah@0 Al@4096 Bh@8192 Bl@16384
  const int t = threadIdx.x;
  const int lane = t & 63, wid = t >> 6, quad = lane >> 4, lrow = lane & 15;
  const int wr = wid >> 1, wc = wid & 1;
  const int lrow4 = lane >> 2, lpos = lane & 3;

  f32x4 acc[2][4];
#pragma unroll
  for (int mi = 0; mi < 2; ++mi)
#pragma unroll
    for (int ni = 0; ni < 4; ++ni) acc[mi][ni] = (f32x4){0.f, 0.f, 0.f, 0.f};

  const char* asrc[2] = {(const char*)(WgH + (size_t)co0 * C_),
                         (const char*)(WgL + (size_t)co0 * C_)};
  const char* bsrc[2] = {(const char*)(xhT + (size_t)(b * N_ + n0) * C_),
                         (const char*)(xlT + (size_t)(b * N_ + n0) * C_)};

  auto stage = [&](int it) {
    char* dst = sm[it & 1];
    const int ktB = it * 64;
#pragma unroll
    for (int i = 0; i < 6; ++i) {
      const int c = wid * 6 + i;
      const char* src;
      int base, row;
      if (c < 8) {
        const int arr = c >> 2, sub = c & 3;
        src = asrc[arr];
        base = arr * 4096 + sub * 1024;
        row = sub * 16 + lrow4;
      } else {
        const int cc = c - 8, arr = cc >> 3, sub = cc & 7;
        src = bsrc[arr];
        base = 8192 + arr * 8192 + sub * 1024;
        row = sub * 16 + lrow4;
      }
      const int swz = lpos ^ ((row >> 1) & 3);
      gld_lds16(src + (size_t)row * 768 + ktB + swz * 16, dst + base + lane * 16);
    }
  };

  stage(0);
  for (int it = 0; it < 12; ++it) {
    __syncthreads();
    if (it < 11) stage(it + 1);
    const char* smb = sm[it & 1];
    f16x8 bh[4], bl[4];
#pragma unroll
    for (int ni = 0; ni < 4; ++ni) {
      const int row = wr * 64 + ni * 16 + lrow;
      const int off = row * 64 + (quad ^ ((row >> 1) & 3)) * 16;
      bh[ni] = *(const f16x8*)(smb + 8192 + off);
      bl[ni] = *(const f16x8*)(smb + 16384 + off);
    }
#pragma unroll
    for (int mi = 0; mi < 2; ++mi) {
      const int row = wc * 32 + mi * 16 + lrow;
      const int off = row * 64 + (quad ^ ((row >> 1) & 3)) * 16;
      f16x8 ah = *(const f16x8*)(smb + off);
      f16x8 al = *(const f16x8*)(smb + 4096 + off);
#pragma unroll
      for (int ni = 0; ni < 4; ++ni) {
        acc[mi][ni] = __builtin_amdgcn_mfma_f32_16x16x32_f16(ah, bh[ni], acc[mi][ni], 0, 0, 0);
        acc[mi][ni] = __builtin_amdgcn_mfma_f32_16x16x32_f16(al, bh[ni], acc[mi][ni], 0, 0, 0);
        acc[mi][ni] = __builtin_amdgcn_mfma_f32_16x16x32_f16(ah, bl[ni], acc[mi][ni], 0, 0, 0);
      }
    }
  }
#pragma unroll
  for (int mi = 0; mi < 2; ++mi)
#pragma unroll
    for (int ni = 0; ni < 4; ++ni)
#pragma unroll
      for (int r = 0; r < 4; ++r) {
        const int c_g = co0 + wc * 32 + mi * 16 + quad * 4 + r;
        const int n_g = n0 + wr * 64 + ni * 16 + lrow;
        xw[((size_t)b * C_ + c_g) * N_ + n_g] = acc[mi][ni][r];
      }
}

// ---------------- aggregate (deg==10 uniformly) + BN partial stats ----------------
__global__ __launch_bounds__(256) void k_agg(const float* __restrict__ xw,
                                             const int* __restrict__ nbr,
                                             const float* __restrict__ bg,
                                             float* __restrict__ out,
                                             float* __restrict__ stats) {
  const int c = blockIdx.x % C_;
  const int b = blockIdx.x / C_;
  __shared__ alignas(16) int nb_l[N_ * K_];
  __shared__ alignas(16) float row_l[N_];
  __shared__ float w1[4], w2[4];
  const int tid = threadIdx.x;
  const int4* gp = (const int4*)(nbr + (size_t)b * N_ * K_);
  int4* lp = (int4*)nb_l;
  for (int t = tid; t < N_ * K_ / 4; t += 256) lp[t] = gp[t];
  const float4* rp = (const float4*)(xw + ((size_t)b * C_ + c) * N_);
  float4* rl = (float4*)row_l;
  for (int t = tid; t < N_ / 4; t += 256) rl[t] = rp[t];
  __syncthreads();
  const float bgc = bg[c];
  float* outb = out + ((size_t)b * C_ + c) * N_;
  float s1 = 0.f, s2 = 0.f;
#pragma unroll
  for (int s = 0; s < 4; ++s) {
    const int n = tid + 256 * s;
    float a = row_l[n];
    const int* nn_ = &nb_l[n * K_];
#pragma unroll
    for (int k = 0; k < K_; ++k) a += row_l[nn_[k]];
    float y = fmaf(a, 0.099999994f, bgc);
    outb[n] = y;
    s1 += y;
    s2 = fmaf(y, y, s2);
  }
#pragma unroll
  for (int off = 32; off > 0; off >>= 1) {
    s1 += __shfl_down(s1, off, 64);
    s2 += __shfl_down(s2, off, 64);
  }
  const int lane = tid & 63, wid = tid >> 6;
  if (lane == 0) { w1[wid] = s1; w2[wid] = s2; }
  __syncthreads();
  if (tid == 0) {
    atomicAdd(&stats[c], w1[0] + w1[1] + w1[2] + w1[3]);
    atomicAdd(&stats[C_ + c], w2[0] + w2[1] + w2[2] + w2[3]);
  }
}

// ---------------- BN (batch stats) + tanh-GELU + residual ----------------
__global__ void k_bn(const float* __restrict__ x, const float* __restrict__ gamma,
                     const float* __restrict__ beta, const float* __restrict__ stats,
                     float* __restrict__ out) {
  const int f = blockIdx.x * blockDim.x + threadIdx.x;
  const int e = f * 4;
  const int c = (e >> 10) % C_;
  const float inv = 1.f / 16384.f;
  const float mu = stats[c] * inv;
  const float var = fmaf(-mu, mu, stats[C_ + c] * inv);
  const float sc = gamma[c] * rsqrtf(var + 1e-5f);
  const float sh = fmaf(-mu, sc, beta[c]);
  float4 y = ((const float4*)out)[f];
  float4 xv = ((const float4*)x)[f];
  auto gl = [](float z) {
    float z3 = z * z * z;
    float t = 0.7978845608028654f * fmaf(0.044715f, z3, z);
    float th = tanhf(t);
    return 0.5f * z * (1.f + th);
  };
  float4 o;
  o.x = gl(fmaf(y.x, sc, sh)) + xv.x;
  o.y = gl(fmaf(y.y, sc, sh)) + xv.y;
  o.z = gl(fmaf(y.z, sc, sh)) + xv.z;
  o.w = gl(fmaf(y.w, sc, sh)) + xv.w;
  ((float4*)out)[f] = o;
}

extern "C" void kernel_launch(void* const* d_in, const int* in_sizes, int n_in,
                              void* d_out, int out_size, void* d_ws, size_t ws_size,
                              hipStream_t stream) {
  const float* x = (const float*)d_in[0];
  const float* Wg = (const float*)d_in[1];
  const float* bg = (const float*)d_in[2];
  const float* gamma = (const float*)d_in[3];
  const float* beta = (const float*)d_in[4];
  float* out = (float*)d_out;

  // layout (51,579,904 B total == R4/R5 proven footprint)
  char* ws = (char*)d_ws;
  ushort* xhT = (ushort*)ws;                  // @0          12,582,912
  ushort* xlT = (ushort*)(ws + 12582912);     //             12,582,912
  ushort* WgH = (ushort*)(ws + 25165824);     //                294,912
  ushort* WgL = (ushort*)(ws + 25460736);     //                294,912
  float* sq = (float*)(ws + 25755648);        //                 65,536
  u64* ck = (u64*)(ws + 25821184);            //              9,437,184 (dead after merge)
  float* xw = (float*)(ws + 25821184);        // overlays ck: 25,165,824
  int* nbr = (int*)(ws + 50987008);           //                589,824
  float* stats = (float*)(ws + 51576832);     //                  3,072

  hipMemsetAsync(stats, 0, 2 * C_ * sizeof(float), stream);
  k_cvt<<<3072, 256, 0, stream>>>(x, xhT, xlT);
  k_cvtw<<<144, 256, 0, stream>>>(Wg, WgH, WgL);
  k_sq<<<64, 256, 0, stream>>>(x, sq);
  k_gram<<<1024, 256, 0, stream>>>(xhT, xlT, sq, ck);
  k_merge<<<64, 256, 0, stream>>>(ck, nbr);
  k_xw<<<768, 256, 0, stream>>>(xhT, xlT, WgH, WgL, xw);  // xw overlays ck (dead)
  k_agg<<<B_ * C_, 256, 0, stream>>>(xw, nbr, bg, out, stats);
  k_bn<<<6144, 256, 0, stream>>>(x, gamma, beta, stats, out);
}